// Round 9
// baseline (1708.699 us; speedup 1.0000x reference)
//
#include <hip/hip_runtime.h>
#include <hip/hip_cooperative_groups.h>
#include <cstddef>

namespace cg = cooperative_groups;

namespace {
constexpr int kNH  = 4;
constexpr int kKD  = 16;
constexpr int kHD  = 64;
constexpr int kD   = 64;
constexpr int kRES = 40;
constexpr int kN   = 1600;   // 40*40
constexpr int kB   = 16;
constexpr int kDIM = 256;
constexpr int kQT  = kN / 32;        // 50 query tiles
constexpr int kNC  = 5;              // key chunks (split-K)
constexpr int kTPC = kQT / kNC;      // 10 key tiles per chunk
constexpr int kGrid = 768;           // 3 blocks/CU x 256 CUs (co-resident)
constexpr float kEPS   = 1e-5f;
constexpr float kSCALE = 0.25f;          // KD^-0.5
constexpr float kLOG2E = 1.4426950408889634f;
constexpr float kC1    = kSCALE * kLOG2E;
}  // namespace

typedef __attribute__((ext_vector_type(8)))  short short8;
typedef __attribute__((ext_vector_type(4)))  short s16x4;
typedef __attribute__((ext_vector_type(4)))  float f32x4;
typedef __attribute__((ext_vector_type(16))) float f32x16;

// f32 -> bf16 bits, round-nearest-even (values here are finite).
static __device__ __forceinline__ unsigned short f2bf(float x) {
  unsigned u = __builtin_bit_cast(unsigned, x);
  u = (u + 0x7fffu + ((u >> 16) & 1u)) >> 16;
  return (unsigned short)u;
}

struct Params {
  const float *x, *dw_w, *dw_g, *dw_b, *dw_m, *dw_v;
  const float *q_w, *q_g, *q_b, *q_m, *q_v;
  const float *k_w, *k_g, *k_b, *k_m, *k_v;
  const float *v_w, *v_g, *v_b, *v_m, *v_v;
  const float *proj_w, *proj_g, *proj_b, *proj_m, *proj_v, *attn_bias;
  float *cbn, *bias2, *psc, *psh, *qkv_sc, *qkv_sh;
  unsigned short *q_t, *k_t, *v_p, *o_bf, *w_bf, *x_t, *w_qk, *w_vv;
  float *o_part, *ml_part;
  float *out;
};

// ===========================================================================
// Device bodies (verified logic from rounds 3-7), shared by both launch paths.
// ===========================================================================

static __device__ __forceinline__ void prep_body(int i, const Params& p) {
  if (i < kNH * kN) p.bias2[i] = p.attn_bias[i] * kLOG2E;
  if (i < kDIM * kDIM) p.w_bf[i] = f2bf(p.proj_w[i]);
  if (i < kDIM) {
    const float sc = p.proj_g[i] * rsqrtf(p.proj_v[i] + kEPS);
    p.psc[i] = sc;
    p.psh[i] = p.proj_b[i] - p.proj_m[i] * sc;
  }
  if (i < kNH * 32 * kHD) {  // (head, ch[0,32), c) ; ch<16 q, else k
    const int head = i >> 11;
    const int ch = (i >> 6) & 31;
    const int c = i & 63;
    const float wv = (ch < 16) ? p.q_w[head * 1024 + ch * 64 + c]
                               : p.k_w[head * 1024 + (ch - 16) * 64 + c];
    p.w_qk[i] = f2bf(wv);
  }
  if (i < kNH * kD * kHD) p.w_vv[i] = f2bf(p.v_w[i]);
  if (i < kNH * 96) {
    const int head = i / 96;
    const int ch = i - head * 96;
    float g, bb, mm, vv;
    if (ch < 16) {
      const int r = head * 16 + ch;
      g = p.q_g[r]; bb = p.q_b[r]; mm = p.q_m[r]; vv = p.q_v[r];
    } else if (ch < 32) {
      const int r = head * 16 + (ch - 16);
      g = p.k_g[r]; bb = p.k_b[r]; mm = p.k_m[r]; vv = p.k_v[r];
    } else {
      const int r = head * 64 + (ch - 32);
      g = p.v_g[r]; bb = p.v_b[r]; mm = p.v_m[r]; vv = p.v_v[r];
    }
    const float sc = g * rsqrtf(vv + kEPS);
    p.qkv_sc[i] = sc;
    p.qkv_sh[i] = bb - mm * sc;
  }
}

// One virtual block per (b, gc). Includes trailing barrier for LDS reuse.
static __device__ void conv_body(int vb, int tid, float* P, const Params& p) {
  const int b = vb >> 8;
  const int gc = vb & 255;
  const int head = gc >> 6;
  const int c = gc & 63;

  for (int i = tid; i < 44 * 44; i += 256) P[i] = 0.f;
  __syncthreads();

  const float* xin = p.x + ((size_t)b * kDIM + gc) * kN;
  for (int i = tid; i < kN; i += 256) {
    const int r = i / kRES;
    const int col = i - r * kRES;
    P[(r + 2) * 44 + col + 2] = xin[i];
  }

  float wreg[25];
  const float* wc = p.dw_w + (size_t)gc * 25;
#pragma unroll
  for (int t = 0; t < 25; ++t) wreg[t] = wc[t];
  const float sc = p.dw_g[gc] * rsqrtf(p.dw_v[gc] + kEPS);
  const float sh = p.dw_b[gc] - p.dw_m[gc] * sc;

  __syncthreads();

  if (tid < 200) {
    const int h = tid / 5;
    const int w0 = (tid - h * 5) * 8;
    float acc[8] = {};
#pragma unroll
    for (int dh = 0; dh < 5; ++dh) {
      float t[12];
      const float* row = P + (h + dh) * 44 + w0;
#pragma unroll
      for (int i = 0; i < 12; ++i) t[i] = row[i];
#pragma unroll
      for (int j = 0; j < 8; ++j)
#pragma unroll
        for (int i = 0; i < 5; ++i)
          acc[j] = fmaf(t[j + i], wreg[dh * 5 + i], acc[j]);
    }
    float* xo = p.cbn + ((size_t)head * kB * kHD + (size_t)b * kHD + c) * kN +
                h * kRES + w0;
    f32x4 o0, o1;
#pragma unroll
    for (int j = 0; j < 4; ++j) {
      o0[j] = acc[j] * sc + sh;
      o1[j] = acc[4 + j] * sc + sh;
    }
    *(f32x4*)xo = o0;
    *(f32x4*)(xo + 4) = o1;
    if (head == 0) {
      unsigned short* xr = p.x_t + (((size_t)b * kN) + h * kRES + w0) * 64 + c;
#pragma unroll
      for (int j = 0; j < 4; ++j) {
        xr[(size_t)j * 64] = f2bf(o0[j]);
        xr[(size_t)(4 + j) * 64] = f2bf(o1[j]);
      }
    }
  }
  __syncthreads();  // protect LDS before next virtual block reuses it
}

static __device__ void qkv_body(int w, int lane,
                                const unsigned short* __restrict__ x_t,
                                const unsigned short* __restrict__ w_qk,
                                const unsigned short* __restrict__ w_v,
                                const float* __restrict__ qsc,
                                const float* __restrict__ qsh,
                                unsigned short* __restrict__ q_t,
                                unsigned short* __restrict__ k_t,
                                unsigned short* __restrict__ v_p) {
  const int b = w / 150;
  const int r = w - b * 150;
  const int col = lane & 31;
  const int h = lane >> 5;

  if (r < kQT) {  // ---- QK wave ----
    const int n0 = r * 32;
    const unsigned short* ax = w_qk + (size_t)col * 64 + h * 8;
    const unsigned short* bx = x_t + ((size_t)b * kN + n0 + col) * 64 + h * 8;
    f32x16 acc = {};
#pragma unroll
    for (int kk = 0; kk < 4; ++kk) {
      const short8 af = *(const short8*)(ax + kk * 16);
      const short8 bf = *(const short8*)(bx + kk * 16);
      acc = __builtin_amdgcn_mfma_f32_32x32x16_bf16(af, bf, acc, 0, 0, 0);
    }
    const int n = n0 + col;
    unsigned short* qrow = q_t + ((size_t)b * kN + n) * 16;
    unsigned short* krow = k_t + ((size_t)b * kN + n) * 16;
#pragma unroll
    for (int g = 0; g < 4; ++g) {
      const int ch0 = g * 8 + 4 * h;
      const f32x4 s4 = *(const f32x4*)(qsc + ch0);
      const f32x4 h4 = *(const f32x4*)(qsh + ch0);
      s16x4 pk;
#pragma unroll
      for (int j = 0; j < 4; ++j)
        pk[j] = (short)f2bf(acc[g * 4 + j] * s4[j] + h4[j]);
      if (ch0 < 16) *(s16x4*)(qrow + ch0) = pk;
      else          *(s16x4*)(krow + ch0 - 16) = pk;
    }
  } else {  // ---- V wave ----
    const int idx = r - kQT;
    const int dt = idx / kQT;
    const int nt = idx - dt * kQT;
    const int n0 = nt * 32;
    const int d = dt * 32 + col;
    const unsigned short* ax = x_t + ((size_t)b * kN + n0 + col) * 64 + h * 8;
    const unsigned short* bx = w_v + (size_t)d * 64 + h * 8;
    f32x16 acc = {};
#pragma unroll
    for (int kk = 0; kk < 4; ++kk) {
      const short8 af = *(const short8*)(ax + kk * 16);
      const short8 bf = *(const short8*)(bx + kk * 16);
      acc = __builtin_amdgcn_mfma_f32_32x32x16_bf16(af, bf, acc, 0, 0, 0);
    }
    const float sc = qsc[32 + d];
    const float sh = qsh[32 + d];
    unsigned short* vrow = v_p + ((size_t)(b * kD) + d) * kN + n0;
#pragma unroll
    for (int g = 0; g < 4; ++g) {
      const int rr0 = g * 8 + 4 * h;
      const int low = rr0 & 15;
      const int pos = (rr0 & 16) | (low & 3) | ((low & 4) << 1) |
                      ((low & 8) >> 1);  // sigma(chunk start)
      s16x4 pk;
#pragma unroll
      for (int j = 0; j < 4; ++j)
        pk[j] = (short)f2bf(acc[g * 4 + j] * sc + sh);
      *(s16x4*)(vrow + pos) = pk;
    }
  }
}

static __device__ void split_body(int w, int lane,
                                  const unsigned short* __restrict__ q_t,
                                  const unsigned short* __restrict__ k_t,
                                  const unsigned short* __restrict__ v_p,
                                  const float* __restrict__ bs,
                                  float* __restrict__ o_part,
                                  float* __restrict__ ml_part) {
  const int b = w / (kQT * kNC);
  const int rem = w - b * (kQT * kNC);
  const int qt = rem / kNC;
  const int chunk = rem - qt * kNC;
  const int col = lane & 31;
  const int h = lane >> 5;
  const int nq = qt * 32 + col;

  const short8 qf =
      *(const short8*)(q_t + ((size_t)b * kN + nq) * 16 + h * 8);
  const unsigned short* vb0 = v_p + ((size_t)(b * kD) + col) * kN;
  const unsigned short* vb1 = v_p + ((size_t)(b * kD) + 32 + col) * kN;

  f32x16 o0 = {}, o1 = {};
  float m = -3.0e38f, l = 0.f;

  for (int kt = chunk * kTPC; kt < (chunk + 1) * kTPC; ++kt) {
    const int kb = kt * 32;
    const short8 kf =
        *(const short8*)(k_t + ((size_t)b * kN + kb + col) * 16 + h * 8);
    f32x16 c = {};
    c = __builtin_amdgcn_mfma_f32_32x32x16_bf16(kf, qf, c, 0, 0, 0);

    const f32x4 bv0 = *(const f32x4*)(bs + kb + 4 * h);
    const f32x4 bv1 = *(const f32x4*)(bs + kb + 8 + 4 * h);
    const f32x4 bv2 = *(const f32x4*)(bs + kb + 16 + 4 * h);
    const f32x4 bv3 = *(const f32x4*)(bs + kb + 24 + 4 * h);

    float s[16];
#pragma unroll
    for (int r = 0; r < 4; ++r)  s[r]      = fmaf(c[r],      kC1, bv0[r]);
#pragma unroll
    for (int r = 0; r < 4; ++r)  s[4 + r]  = fmaf(c[4 + r],  kC1, bv1[r]);
#pragma unroll
    for (int r = 0; r < 4; ++r)  s[8 + r]  = fmaf(c[8 + r],  kC1, bv2[r]);
#pragma unroll
    for (int r = 0; r < 4; ++r)  s[12 + r] = fmaf(c[12 + r], kC1, bv3[r]);

    float tmax = s[0];
#pragma unroll
    for (int r = 1; r < 16; ++r) tmax = fmaxf(tmax, s[r]);
    tmax = fmaxf(tmax, __shfl_xor(tmax, 32));

    const bool upd = tmax > m + 8.0f;   // defer-max (log2 domain)
    if (__any(upd)) {
      const float alpha = upd ? exp2f(m - tmax) : 1.0f;
      m = upd ? tmax : m;
      l *= alpha;
#pragma unroll
      for (int r = 0; r < 16; ++r) { o0[r] *= alpha; o1[r] *= alpha; }
    }

    short8 p0, p1;
    float lsum = 0.f;
#pragma unroll
    for (int e = 0; e < 8; ++e) {
      const float pe = exp2f(s[e] - m);
      lsum += pe;
      p0[e] = (short)f2bf(pe);
    }
#pragma unroll
    for (int e = 0; e < 8; ++e) {
      const float pe = exp2f(s[8 + e] - m);
      lsum += pe;
      p1[e] = (short)f2bf(pe);
    }
    l += lsum;

    const short8 vf00 = *(const short8*)(vb0 + kb + h * 8);
    const short8 vf01 = *(const short8*)(vb0 + kb + 16 + h * 8);
    const short8 vf10 = *(const short8*)(vb1 + kb + h * 8);
    const short8 vf11 = *(const short8*)(vb1 + kb + 16 + h * 8);
    o0 = __builtin_amdgcn_mfma_f32_32x32x16_bf16(vf00, p0, o0, 0, 0, 0);
    o0 = __builtin_amdgcn_mfma_f32_32x32x16_bf16(vf01, p1, o0, 0, 0, 0);
    o1 = __builtin_amdgcn_mfma_f32_32x32x16_bf16(vf10, p0, o1, 0, 0, 0);
    o1 = __builtin_amdgcn_mfma_f32_32x32x16_bf16(vf11, p1, o1, 0, 0, 0);
  }

  l += __shfl_xor(l, 32);

  float* op = o_part + (size_t)w * 2048 + lane * 32;
#pragma unroll
  for (int r = 0; r < 16; ++r) {
    op[r] = o0[r];
    op[16 + r] = o1[r];
  }
  ml_part[(size_t)w * 128 + lane * 2]     = m;
  ml_part[(size_t)w * 128 + lane * 2 + 1] = l;
}

static __device__ void combine_body(int w, int lane,
                                    const float* __restrict__ o_part,
                                    const float* __restrict__ ml_part,
                                    const float* __restrict__ cbn_next,
                                    unsigned short* __restrict__ x_t_next,
                                    unsigned short* __restrict__ o_bf,
                                    int head, int do_cascade) {
  const int b = w / kQT;
  const int qt = w - b * kQT;
  const int col = lane & 31;
  const int h = lane >> 5;
  const int nq = qt * 32 + col;

  const size_t base = (size_t)w * kNC;
  float mc[kNC], lc[kNC];
  float M = -3.0e38f;
#pragma unroll
  for (int c = 0; c < kNC; ++c) {
    mc[c] = ml_part[(base + c) * 128 + lane * 2];
    lc[c] = ml_part[(base + c) * 128 + lane * 2 + 1];
    M = fmaxf(M, mc[c]);
  }
  float o[32] = {};
  float l_tot = 0.f;
#pragma unroll
  for (int c = 0; c < kNC; ++c) {
    const float sc = exp2f(mc[c] - M);
    l_tot = fmaf(lc[c], sc, l_tot);
    const float* op = o_part + (base + c) * 2048 + lane * 32;
#pragma unroll
    for (int r = 0; r < 32; ++r) o[r] = fmaf(op[r], sc, o[r]);
  }
  const float inv = 1.0f / l_tot;

  unsigned short* obf = o_bf + ((size_t)b * kN + nq) * kDIM + head * kD;
  if (do_cascade) {
    const float* cb = cbn_next + (size_t)b * kHD * kN + nq;
    unsigned short* xrow = x_t_next + ((size_t)b * kN + nq) * 64;
#pragma unroll
    for (int g = 0; g < 4; ++g) {
      const int d0 = g * 8 + 4 * h;
      s16x4 po0, po1, px0, px1;
#pragma unroll
      for (int j = 0; j < 4; ++j) {
        const int dim = d0 + j;
        const float v0 = o[g * 4 + j] * inv;
        const float v1 = o[16 + g * 4 + j] * inv;
        po0[j] = (short)f2bf(v0);
        po1[j] = (short)f2bf(v1);
        px0[j] = (short)f2bf(cb[(size_t)dim * kN] + v0);
        px1[j] = (short)f2bf(cb[(size_t)(dim + 32) * kN] + v1);
      }
      *(s16x4*)(obf + d0) = po0;
      *(s16x4*)(obf + d0 + 32) = po1;
      *(s16x4*)(xrow + d0) = px0;
      *(s16x4*)(xrow + d0 + 32) = px1;
    }
  } else {
#pragma unroll
    for (int g = 0; g < 4; ++g) {
      const int d0 = g * 8 + 4 * h;
      s16x4 po0, po1;
#pragma unroll
      for (int j = 0; j < 4; ++j) {
        po0[j] = (short)f2bf(o[g * 4 + j] * inv);
        po1[j] = (short)f2bf(o[16 + g * 4 + j] * inv);
      }
      *(s16x4*)(obf + d0) = po0;
      *(s16x4*)(obf + d0 + 32) = po1;
    }
  }
}

static __device__ void proj_body(int t, int lane,
                                 const unsigned short* __restrict__ o_bf,
                                 const unsigned short* __restrict__ w_bf,
                                 const float* __restrict__ psc,
                                 const float* __restrict__ psh,
                                 float* __restrict__ out) {
  const int b = t / 400;
  const int rem = t - b * 400;
  const int ot = rem / 50;
  const int nt = rem - ot * 50;
  const int col = lane & 31;
  const int h = lane >> 5;

  const unsigned short* arow = w_bf + ((size_t)(ot * 32 + col)) * kDIM + h * 8;
  const unsigned short* brow =
      o_bf + ((size_t)(b * kN + nt * 32 + col)) * kDIM + h * 8;

  f32x16 acc = {};
#pragma unroll
  for (int k = 0; k < 16; ++k) {
    const short8 af = *(const short8*)(arow + k * 16);
    const short8 bfr = *(const short8*)(brow + k * 16);
    acc = __builtin_amdgcn_mfma_f32_32x32x16_bf16(af, bfr, acc, 0, 0, 0);
  }

  float* ob = out + (size_t)b * kDIM * kN + nt * 32 + col;
#pragma unroll
  for (int r = 0; r < 16; ++r) {
    const int o = ot * 32 + (r & 3) + 8 * (r >> 2) + 4 * h;
    const float v = acc[r] * psc[o] + psh[o];
    ob[(size_t)o * kN] = fmaxf(v, 0.f);
  }
}

// ===========================================================================
// Fused persistent cooperative kernel: 1 dispatch, 13 grid syncs.
// ===========================================================================
__global__ __launch_bounds__(256, 3) void mega_kernel(Params p) {
  cg::grid_group grid = cg::this_grid();
  __shared__ float P[44 * 44];
  const int tid = threadIdx.x;
  const int lane = tid & 63;
  const int wid = tid >> 6;
  const int nblk = gridDim.x;
  const int nw = nblk << 2;
  const int gw = (blockIdx.x << 2) + wid;

  // P0: prep (independent of conv — no sync between them)
  for (int i = blockIdx.x * 256 + tid; i < kDIM * kDIM; i += nblk * 256)
    prep_body(i, p);

  // P1: depthwise conv, 4096 virtual blocks
  for (int vb = blockIdx.x; vb < kB * kDIM; vb += nblk)
    conv_body(vb, tid, P, p);

  grid.sync();

  const size_t cslice = (size_t)kB * kHD * kN;
  const size_t xslice = (size_t)kB * kN * 64;

  for (int head = 0; head < kNH; ++head) {
    const unsigned short* xt = p.x_t + (size_t)head * xslice;
    const unsigned short* wqk = p.w_qk + (size_t)head * 32 * kHD;
    const unsigned short* wv = p.w_vv + (size_t)head * kD * kHD;
    const float* qsc = p.qkv_sc + head * 96;
    const float* qsh = p.qkv_sh + head * 96;
    for (int w = gw; w < kB * 150; w += nw)
      qkv_body(w, lane, xt, wqk, wv, qsc, qsh, p.q_t, p.k_t, p.v_p);
    grid.sync();

    const float* bs = p.bias2 + (size_t)head * kN;
    for (int w = gw; w < kB * kQT * kNC; w += nw)
      split_body(w, lane, p.q_t, p.k_t, p.v_p, bs, p.o_part, p.ml_part);
    grid.sync();

    const int casc = head < 3 ? 1 : 0;
    const float* cbn_next = p.cbn + (size_t)(head + 1) * cslice;
    unsigned short* xt_next =
        casc ? (p.x_t + (size_t)(head + 1) * xslice) : p.x_t;
    for (int w = gw; w < kB * kQT; w += nw)
      combine_body(w, lane, p.o_part, p.ml_part, cbn_next, xt_next, p.o_bf,
                   head, casc);
    grid.sync();
  }

  for (int w = gw; w < kB * 400; w += nw)
    proj_body(w, lane, p.o_bf, p.w_bf, p.psc, p.psh, p.out);
}

// ===========================================================================
// Fallback standalone kernels (round-7 path) — same bodies.
// ===========================================================================
__global__ __launch_bounds__(256) void prep_kernel(Params p) {
  prep_body(blockIdx.x * 256 + threadIdx.x, p);
}
__global__ __launch_bounds__(256) void conv_all_kernel(Params p) {
  __shared__ float P[44 * 44];
  conv_body(blockIdx.x, threadIdx.x, P, p);
}
__global__ __launch_bounds__(256) void qkv_mfma_kernel(Params p, int head) {
  const int w = blockIdx.x * 4 + (threadIdx.x >> 6);
  qkv_body(w, threadIdx.x & 63, p.x_t + (size_t)head * kB * kN * 64,
           p.w_qk + (size_t)head * 32 * kHD, p.w_vv + (size_t)head * kD * kHD,
           p.qkv_sc + head * 96, p.qkv_sh + head * 96, p.q_t, p.k_t, p.v_p);
}
__global__ __launch_bounds__(256) void attn_split_kernel(Params p, int head) {
  const int w = blockIdx.x * 4 + (threadIdx.x >> 6);
  if (w >= kB * kQT * kNC) return;
  split_body(w, threadIdx.x & 63, p.q_t, p.k_t, p.v_p,
             p.bias2 + (size_t)head * kN, p.o_part, p.ml_part);
}
__global__ __launch_bounds__(256) void attn_combine_kernel(Params p, int head) {
  const int w = blockIdx.x * 4 + (threadIdx.x >> 6);
  if (w >= kB * kQT) return;
  const int casc = head < 3 ? 1 : 0;
  const size_t cslice = (size_t)kB * kHD * kN;
  const size_t xslice = (size_t)kB * kN * 64;
  combine_body(w, threadIdx.x & 63, p.o_part, p.ml_part,
               p.cbn + (size_t)(head + 1) * cslice,
               casc ? (p.x_t + (size_t)(head + 1) * xslice) : p.x_t, p.o_bf,
               head, casc);
}
__global__ __launch_bounds__(256) void proj_mfma_kernel(Params p) {
  proj_body(blockIdx.x * 4 + (threadIdx.x >> 6), threadIdx.x & 63, p.o_bf,
            p.w_bf, p.psc, p.psh, p.out);
}

// ===========================================================================
extern "C" void kernel_launch(void* const* d_in, const int* in_sizes, int n_in,
                              void* d_out, int out_size, void* d_ws,
                              size_t ws_size, hipStream_t stream) {
  Params p;
  p.x      = (const float*)d_in[0];
  p.dw_w   = (const float*)d_in[1];
  p.dw_g   = (const float*)d_in[2];
  p.dw_b   = (const float*)d_in[3];
  p.dw_m   = (const float*)d_in[4];
  p.dw_v   = (const float*)d_in[5];
  p.q_w    = (const float*)d_in[6];
  p.q_g    = (const float*)d_in[7];
  p.q_b    = (const float*)d_in[8];
  p.q_m    = (const float*)d_in[9];
  p.q_v    = (const float*)d_in[10];
  p.k_w    = (const float*)d_in[11];
  p.k_g    = (const float*)d_in[12];
  p.k_b    = (const float*)d_in[13];
  p.k_m    = (const float*)d_in[14];
  p.k_v    = (const float*)d_in[15];
  p.v_w    = (const float*)d_in[16];
  p.v_g    = (const float*)d_in[17];
  p.v_b    = (const float*)d_in[18];
  p.v_m    = (const float*)d_in[19];
  p.v_v    = (const float*)d_in[20];
  p.proj_w = (const float*)d_in[21];
  p.proj_g = (const float*)d_in[22];
  p.proj_b = (const float*)d_in[23];
  p.proj_m = (const float*)d_in[24];
  p.proj_v = (const float*)d_in[25];
  p.attn_bias = (const float*)d_in[26];

  float* ws = (float*)d_ws;
  p.cbn    = ws;                                       // 4*B*64*N f32
  p.bias2  = p.cbn + (size_t)kNH * kB * kHD * kN;      // 4*N f32
  p.psc    = p.bias2 + kNH * kN;                       // 256 f32
  p.psh    = p.psc + kDIM;                             // 256 f32
  p.qkv_sc = p.psh + kDIM;                             // 4*96 f32
  p.qkv_sh = p.qkv_sc + kNH * 96;                      // 4*96 f32
  p.q_t  = (unsigned short*)(p.qkv_sh + kNH * 96);     // B*N*16 bf16
  p.k_t  = p.q_t + (size_t)kB * kN * kKD;              // B*N*16
  p.v_p  = p.k_t + (size_t)kB * kN * kKD;              // B*64*N
  p.o_bf = p.v_p + (size_t)kB * kD * kN;               // B*N*256
  p.w_bf = p.o_bf + (size_t)kB * kN * kDIM;            // 256*256
  p.x_t  = p.w_bf + (size_t)kDIM * kDIM;               // 4*B*N*64
  p.w_qk = p.x_t + (size_t)kNH * kB * kN * 64;         // 4*32*64
  p.w_vv = p.w_qk + (size_t)kNH * 32 * kHD;            // 4*64*64
  p.o_part  = (float*)(p.w_vv + (size_t)kNH * kD * kHD);   // B*250*2048 f32
  p.ml_part = p.o_part + (size_t)kB * kQT * kNC * 2048;    // B*250*128 f32
  p.out = (float*)d_out;

  void* kargs[] = {(void*)&p};
  const hipError_t err = hipLaunchCooperativeKernel(
      (const void*)mega_kernel, dim3(kGrid), dim3(256), kargs, 0, stream);

  if (err != hipSuccess) {
    // Fallback: round-7 multi-dispatch path (same device bodies).
    prep_kernel<<<(kDIM * kDIM + 255) / 256, 256, 0, stream>>>(p);
    conv_all_kernel<<<kB * kDIM, 256, 0, stream>>>(p);
    for (int head = 0; head < kNH; ++head) {
      qkv_mfma_kernel<<<600, 256, 0, stream>>>(p, head);
      attn_split_kernel<<<kB * kQT * kNC / 4, 256, 0, stream>>>(p, head);
      attn_combine_kernel<<<kB * kQT / 4, 256, 0, stream>>>(p, head);
    }
    proj_mfma_kernel<<<1600, 256, 0, stream>>>(p);
  }
}

// Round 10
// 351.998 us; speedup vs baseline: 4.8543x; 4.8543x over previous
//
#include <hip/hip_runtime.h>
#include <cstddef>

namespace {
constexpr int kNH  = 4;
constexpr int kKD  = 16;
constexpr int kHD  = 64;
constexpr int kD   = 64;
constexpr int kRES = 40;
constexpr int kN   = 1600;   // 40*40
constexpr int kB   = 16;
constexpr int kDIM = 256;
constexpr int kQT  = kN / 32;        // 50 query tiles
constexpr float kEPS   = 1e-5f;
constexpr float kSCALE = 0.25f;          // KD^-0.5
constexpr float kLOG2E = 1.4426950408889634f;
constexpr float kC1    = kSCALE * kLOG2E;
}  // namespace

typedef __attribute__((ext_vector_type(8)))  short short8;
typedef __attribute__((ext_vector_type(4)))  short s16x4;
typedef __attribute__((ext_vector_type(4)))  float f32x4;
typedef __attribute__((ext_vector_type(16))) float f32x16;

// f32 -> bf16 bits, round-nearest-even (values here are finite).
static __device__ __forceinline__ unsigned short f2bf(float x) {
  unsigned u = __builtin_bit_cast(unsigned, x);
  u = (u + 0x7fffu + ((u >> 16) & 1u)) >> 16;
  return (unsigned short)u;
}

struct Params {
  const float *x, *dw_w, *dw_g, *dw_b, *dw_m, *dw_v;
  const float *q_w, *q_g, *q_b, *q_m, *q_v;
  const float *k_w, *k_g, *k_b, *k_m, *k_v;
  const float *v_w, *v_g, *v_b, *v_m, *v_v;
  const float *proj_w, *proj_g, *proj_b, *proj_m, *proj_v, *attn_bias;
  float *cbn, *bias2, *psc, *psh, *qkv_sc, *qkv_sh;
  unsigned short *q_t, *k_t, *v_p, *o_bf, *w_bf, *x_t, *w_qk, *w_vv;
  float *out;
};

// ===========================================================================
// Device bodies (verified, rounds 3-7).
// ===========================================================================

static __device__ __forceinline__ void prep_body(int i, const Params& p) {
  if (i < kNH * kN) p.bias2[i] = p.attn_bias[i] * kLOG2E;
  if (i < kDIM * kDIM) p.w_bf[i] = f2bf(p.proj_w[i]);
  if (i < kDIM) {
    const float sc = p.proj_g[i] * rsqrtf(p.proj_v[i] + kEPS);
    p.psc[i] = sc;
    p.psh[i] = p.proj_b[i] - p.proj_m[i] * sc;
  }
  if (i < kNH * 32 * kHD) {  // (head, ch[0,32), c) ; ch<16 q, else k
    const int head = i >> 11;
    const int ch = (i >> 6) & 31;
    const int c = i & 63;
    const float wv = (ch < 16) ? p.q_w[head * 1024 + ch * 64 + c]
                               : p.k_w[head * 1024 + (ch - 16) * 64 + c];
    p.w_qk[i] = f2bf(wv);
  }
  if (i < kNH * kD * kHD) p.w_vv[i] = f2bf(p.v_w[i]);
  if (i < kNH * 96) {
    const int head = i / 96;
    const int ch = i - head * 96;
    float g, bb, mm, vv;
    if (ch < 16) {
      const int r = head * 16 + ch;
      g = p.q_g[r]; bb = p.q_b[r]; mm = p.q_m[r]; vv = p.q_v[r];
    } else if (ch < 32) {
      const int r = head * 16 + (ch - 16);
      g = p.k_g[r]; bb = p.k_b[r]; mm = p.k_m[r]; vv = p.k_v[r];
    } else {
      const int r = head * 64 + (ch - 32);
      g = p.v_g[r]; bb = p.v_b[r]; mm = p.v_m[r]; vv = p.v_v[r];
    }
    const float sc = g * rsqrtf(vv + kEPS);
    p.qkv_sc[i] = sc;
    p.qkv_sh[i] = bb - mm * sc;
  }
}

// ===========================================================================
// Kernel 1: prep (blocks 0-255) + depthwise 5x5 conv + BN, all 4 heads.
// ===========================================================================
__global__ __launch_bounds__(256) void conv_prep_kernel(Params p) {
  const int blk = blockIdx.x;          // b*256 + gc
  const int tid = threadIdx.x;
  if (blk < 256) prep_body(blk * 256 + tid, p);

  __shared__ float P[44 * 44];
  const int b = blk >> 8;
  const int gc = blk & 255;
  const int head = gc >> 6;
  const int c = gc & 63;

  for (int i = tid; i < 44 * 44; i += 256) P[i] = 0.f;
  __syncthreads();

  const float* xin = p.x + ((size_t)b * kDIM + gc) * kN;
  for (int i = tid; i < kN; i += 256) {
    const int r = i / kRES;
    const int col = i - r * kRES;
    P[(r + 2) * 44 + col + 2] = xin[i];
  }

  float wreg[25];
  const float* wc = p.dw_w + (size_t)gc * 25;
#pragma unroll
  for (int t = 0; t < 25; ++t) wreg[t] = wc[t];
  const float sc = p.dw_g[gc] * rsqrtf(p.dw_v[gc] + kEPS);
  const float sh = p.dw_b[gc] - p.dw_m[gc] * sc;

  __syncthreads();

  if (tid < 200) {
    const int h = tid / 5;
    const int w0 = (tid - h * 5) * 8;
    float acc[8] = {};
#pragma unroll
    for (int dh = 0; dh < 5; ++dh) {
      float t[12];
      const float* row = P + (h + dh) * 44 + w0;
#pragma unroll
      for (int i = 0; i < 12; ++i) t[i] = row[i];
#pragma unroll
      for (int j = 0; j < 8; ++j)
#pragma unroll
        for (int i = 0; i < 5; ++i)
          acc[j] = fmaf(t[j + i], wreg[dh * 5 + i], acc[j]);
    }
    float* xo = p.cbn + ((size_t)head * kB * kHD + (size_t)b * kHD + c) * kN +
                h * kRES + w0;
    f32x4 o0, o1;
#pragma unroll
    for (int j = 0; j < 4; ++j) {
      o0[j] = acc[j] * sc + sh;
      o1[j] = acc[4 + j] * sc + sh;
    }
    *(f32x4*)xo = o0;
    *(f32x4*)(xo + 4) = o1;
    if (head == 0) {
      unsigned short* xr = p.x_t + (((size_t)b * kN) + h * kRES + w0) * 64 + c;
#pragma unroll
      for (int j = 0; j < 4; ++j) {
        xr[(size_t)j * 64] = f2bf(o0[j]);
        xr[(size_t)(4 + j) * 64] = f2bf(o1[j]);
      }
    }
  }
}

// ===========================================================================
// Kernel 2: fused QKV via MFMA (verified round-7 body).
// ===========================================================================
__global__ __launch_bounds__(256) void qkv_mfma_kernel(Params p, int head) {
  const int lane = threadIdx.x & 63;
  const int w = blockIdx.x * 4 + (threadIdx.x >> 6);   // [0, 2400)
  const unsigned short* x_t = p.x_t + (size_t)head * kB * kN * 64;
  const unsigned short* w_qk = p.w_qk + (size_t)head * 32 * kHD;
  const unsigned short* w_v = p.w_vv + (size_t)head * kD * kHD;
  const float* qsc = p.qkv_sc + head * 96;
  const float* qsh = p.qkv_sh + head * 96;

  const int b = w / 150;
  const int r = w - b * 150;
  const int col = lane & 31;
  const int h = lane >> 5;

  if (r < kQT) {  // ---- QK wave ----
    const int n0 = r * 32;
    const unsigned short* ax = w_qk + (size_t)col * 64 + h * 8;
    const unsigned short* bx = x_t + ((size_t)b * kN + n0 + col) * 64 + h * 8;
    f32x16 acc = {};
#pragma unroll
    for (int kk = 0; kk < 4; ++kk) {
      const short8 af = *(const short8*)(ax + kk * 16);
      const short8 bf = *(const short8*)(bx + kk * 16);
      acc = __builtin_amdgcn_mfma_f32_32x32x16_bf16(af, bf, acc, 0, 0, 0);
    }
    const int n = n0 + col;
    unsigned short* qrow = p.q_t + ((size_t)b * kN + n) * 16;
    unsigned short* krow = p.k_t + ((size_t)b * kN + n) * 16;
#pragma unroll
    for (int g = 0; g < 4; ++g) {
      const int ch0 = g * 8 + 4 * h;
      const f32x4 s4 = *(const f32x4*)(qsc + ch0);
      const f32x4 h4 = *(const f32x4*)(qsh + ch0);
      s16x4 pk;
#pragma unroll
      for (int j = 0; j < 4; ++j)
        pk[j] = (short)f2bf(acc[g * 4 + j] * s4[j] + h4[j]);
      if (ch0 < 16) *(s16x4*)(qrow + ch0) = pk;
      else          *(s16x4*)(krow + ch0 - 16) = pk;
    }
  } else {  // ---- V wave ----
    const int idx = r - kQT;
    const int dt = idx / kQT;
    const int nt = idx - dt * kQT;
    const int n0 = nt * 32;
    const int d = dt * 32 + col;
    const unsigned short* ax = x_t + ((size_t)b * kN + n0 + col) * 64 + h * 8;
    const unsigned short* bx = w_v + (size_t)d * 64 + h * 8;
    f32x16 acc = {};
#pragma unroll
    for (int kk = 0; kk < 4; ++kk) {
      const short8 af = *(const short8*)(ax + kk * 16);
      const short8 bf = *(const short8*)(bx + kk * 16);
      acc = __builtin_amdgcn_mfma_f32_32x32x16_bf16(af, bf, acc, 0, 0, 0);
    }
    const float sc = qsc[32 + d];
    const float sh = qsh[32 + d];
    unsigned short* vrow = p.v_p + ((size_t)(b * kD) + d) * kN + n0;
#pragma unroll
    for (int g = 0; g < 4; ++g) {
      const int rr0 = g * 8 + 4 * h;
      const int low = rr0 & 15;
      const int pos = (rr0 & 16) | (low & 3) | ((low & 4) << 1) |
                      ((low & 8) >> 1);  // sigma(chunk start)
      s16x4 pk;
#pragma unroll
      for (int j = 0; j < 4; ++j)
        pk[j] = (short)f2bf(acc[g * 4 + j] * sc + sh);
      *(s16x4*)(vrow + pos) = pk;
    }
  }
}

// ===========================================================================
// Kernel 3: fused flash attention. One block = one (b, qt): 4 waves each
// flash an interleaved quarter of the 50 key tiles (verified tile body),
// partials combined through padded LDS (no global o_part round-trip),
// epilogue writes o_bf + fused cascade into cbn_next/x_t_next.
// ===========================================================================
__global__ __launch_bounds__(256) void attn_fused_kernel(Params p, int head) {
  __shared__ float so[4][64][33];     // [chunk][src lane][r], +1 pad
  __shared__ float sml[4][32][2];     // [chunk][query col][m,l]
  const int tid = threadIdx.x;
  const int lane = tid & 63;
  const int wv = tid >> 6;            // chunk id, 0..3
  const int blk = blockIdx.x;         // b*50 + qt
  const int b = blk / kQT;
  const int qt = blk - b * kQT;
  const int col = lane & 31;
  const int h = lane >> 5;
  const int nq = qt * 32 + col;

  const short8 qf =
      *(const short8*)(p.q_t + ((size_t)b * kN + nq) * 16 + h * 8);
  const float* bs = p.bias2 + (size_t)head * kN;
  const unsigned short* vb0 = p.v_p + ((size_t)(b * kD) + col) * kN;
  const unsigned short* vb1 = p.v_p + ((size_t)(b * kD) + 32 + col) * kN;

  f32x16 o0 = {}, o1 = {};
  float m = -3.0e38f, l = 0.f;

  for (int kt = wv; kt < kQT; kt += 4) {
    const int kb = kt * 32;
    const short8 kf =
        *(const short8*)(p.k_t + ((size_t)b * kN + kb + col) * 16 + h * 8);
    f32x16 c = {};
    c = __builtin_amdgcn_mfma_f32_32x32x16_bf16(kf, qf, c, 0, 0, 0);

    const f32x4 bv0 = *(const f32x4*)(bs + kb + 4 * h);
    const f32x4 bv1 = *(const f32x4*)(bs + kb + 8 + 4 * h);
    const f32x4 bv2 = *(const f32x4*)(bs + kb + 16 + 4 * h);
    const f32x4 bv3 = *(const f32x4*)(bs + kb + 24 + 4 * h);

    float s[16];
#pragma unroll
    for (int r = 0; r < 4; ++r)  s[r]      = fmaf(c[r],      kC1, bv0[r]);
#pragma unroll
    for (int r = 0; r < 4; ++r)  s[4 + r]  = fmaf(c[4 + r],  kC1, bv1[r]);
#pragma unroll
    for (int r = 0; r < 4; ++r)  s[8 + r]  = fmaf(c[8 + r],  kC1, bv2[r]);
#pragma unroll
    for (int r = 0; r < 4; ++r)  s[12 + r] = fmaf(c[12 + r], kC1, bv3[r]);

    float tmax = s[0];
#pragma unroll
    for (int r = 1; r < 16; ++r) tmax = fmaxf(tmax, s[r]);
    tmax = fmaxf(tmax, __shfl_xor(tmax, 32));

    const bool upd = tmax > m + 8.0f;   // defer-max (log2 domain)
    if (__any(upd)) {
      const float alpha = upd ? exp2f(m - tmax) : 1.0f;
      m = upd ? tmax : m;
      l *= alpha;
#pragma unroll
      for (int r = 0; r < 16; ++r) { o0[r] *= alpha; o1[r] *= alpha; }
    }

    short8 p0, p1;
    float lsum = 0.f;
#pragma unroll
    for (int e = 0; e < 8; ++e) {
      const float pe = exp2f(s[e] - m);
      lsum += pe;
      p0[e] = (short)f2bf(pe);
    }
#pragma unroll
    for (int e = 0; e < 8; ++e) {
      const float pe = exp2f(s[8 + e] - m);
      lsum += pe;
      p1[e] = (short)f2bf(pe);
    }
    l += lsum;

    const short8 vf00 = *(const short8*)(vb0 + kb + h * 8);
    const short8 vf01 = *(const short8*)(vb0 + kb + 16 + h * 8);
    const short8 vf10 = *(const short8*)(vb1 + kb + h * 8);
    const short8 vf11 = *(const short8*)(vb1 + kb + 16 + h * 8);
    o0 = __builtin_amdgcn_mfma_f32_32x32x16_bf16(vf00, p0, o0, 0, 0, 0);
    o0 = __builtin_amdgcn_mfma_f32_32x32x16_bf16(vf01, p1, o0, 0, 0, 0);
    o1 = __builtin_amdgcn_mfma_f32_32x32x16_bf16(vf10, p0, o1, 0, 0, 0);
    o1 = __builtin_amdgcn_mfma_f32_32x32x16_bf16(vf11, p1, o1, 0, 0, 0);
  }

  l += __shfl_xor(l, 32);  // both halves hold the query's full chunk-l

  // Stash partials in LDS.
#pragma unroll
  for (int r = 0; r < 16; ++r) {
    so[wv][lane][r] = o0[r];
    so[wv][lane][16 + r] = o1[r];
  }
  if (h == 0) {
    sml[wv][col][0] = m;
    sml[wv][col][1] = l;
  }
  __syncthreads();

  // Block combine: thread (wv, lane) owns r-octet [wv*8, wv*8+8) of source
  // lane `lane` (its own query col / h).
  float mc[4], lc[4];
  float M = -3.0e38f;
#pragma unroll
  for (int c = 0; c < 4; ++c) {
    mc[c] = sml[c][col][0];
    lc[c] = sml[c][col][1];
    M = fmaxf(M, mc[c]);
  }
  float scale[4];
  float lt = 0.f;
#pragma unroll
  for (int c = 0; c < 4; ++c) {
    scale[c] = exp2f(mc[c] - M);
    lt = fmaf(lc[c], scale[c], lt);
  }
  const float inv = 1.0f / lt;

  const int r0 = wv * 8;
  float ov[8];
#pragma unroll
  for (int j = 0; j < 8; ++j) {
    float a = 0.f;
#pragma unroll
    for (int c = 0; c < 4; ++c) a = fmaf(so[c][lane][r0 + j], scale[c], a);
    ov[j] = a * inv;
  }

  // r-octet -> output dims: base = wv*16; dims {base+4h+j} and {base+8+4h+j}.
  const int d0a = wv * 16 + 4 * h;
  const int d0b = d0a + 8;
  unsigned short* obf = p.o_bf + ((size_t)b * kN + nq) * kDIM + head * kD;
  s16x4 pa, pb;
  if (head < 3) {
    const float* cb = p.cbn + (size_t)(head + 1) * kB * kHD * kN +
                      (size_t)b * kHD * kN + nq;
    unsigned short* xrow = p.x_t + (size_t)(head + 1) * kB * kN * 64 +
                           ((size_t)b * kN + nq) * 64;
    s16x4 xa, xb;
#pragma unroll
    for (int j = 0; j < 4; ++j) {
      pa[j] = (short)f2bf(ov[j]);
      pb[j] = (short)f2bf(ov[4 + j]);
      xa[j] = (short)f2bf(cb[(size_t)(d0a + j) * kN] + ov[j]);
      xb[j] = (short)f2bf(cb[(size_t)(d0b + j) * kN] + ov[4 + j]);
    }
    *(s16x4*)(obf + d0a) = pa;
    *(s16x4*)(obf + d0b) = pb;
    *(s16x4*)(xrow + d0a) = xa;
    *(s16x4*)(xrow + d0b) = xb;
  } else {
#pragma unroll
    for (int j = 0; j < 4; ++j) {
      pa[j] = (short)f2bf(ov[j]);
      pb[j] = (short)f2bf(ov[4 + j]);
    }
    *(s16x4*)(obf + d0a) = pa;
    *(s16x4*)(obf + d0b) = pb;
  }
}

// ===========================================================================
// Kernel 4: projection GEMM via MFMA (verified round-7 body).
// ===========================================================================
__global__ __launch_bounds__(256) void proj_mfma_kernel(Params p) {
  const int lane = threadIdx.x & 63;
  const int t = blockIdx.x * 4 + (threadIdx.x >> 6);   // [0, 6400)
  const int b = t / 400;
  const int rem = t - b * 400;
  const int ot = rem / 50;
  const int nt = rem - ot * 50;
  const int col = lane & 31;
  const int h = lane >> 5;

  const unsigned short* arow =
      p.w_bf + ((size_t)(ot * 32 + col)) * kDIM + h * 8;
  const unsigned short* brow =
      p.o_bf + ((size_t)(b * kN + nt * 32 + col)) * kDIM + h * 8;

  f32x16 acc = {};
#pragma unroll
  for (int k = 0; k < 16; ++k) {
    const short8 af = *(const short8*)(arow + k * 16);
    const short8 bfr = *(const short8*)(brow + k * 16);
    acc = __builtin_amdgcn_mfma_f32_32x32x16_bf16(af, bfr, acc, 0, 0, 0);
  }

  float* ob = p.out + (size_t)b * kDIM * kN + nt * 32 + col;
#pragma unroll
  for (int r = 0; r < 16; ++r) {
    const int o = ot * 32 + (r & 3) + 8 * (r >> 2) + 4 * h;
    const float v = acc[r] * p.psc[o] + p.psh[o];
    ob[(size_t)o * kN] = fmaxf(v, 0.f);
  }
}

// ===========================================================================
extern "C" void kernel_launch(void* const* d_in, const int* in_sizes, int n_in,
                              void* d_out, int out_size, void* d_ws,
                              size_t ws_size, hipStream_t stream) {
  Params p;
  p.x      = (const float*)d_in[0];
  p.dw_w   = (const float*)d_in[1];
  p.dw_g   = (const float*)d_in[2];
  p.dw_b   = (const float*)d_in[3];
  p.dw_m   = (const float*)d_in[4];
  p.dw_v   = (const float*)d_in[5];
  p.q_w    = (const float*)d_in[6];
  p.q_g    = (const float*)d_in[7];
  p.q_b    = (const float*)d_in[8];
  p.q_m    = (const float*)d_in[9];
  p.q_v    = (const float*)d_in[10];
  p.k_w    = (const float*)d_in[11];
  p.k_g    = (const float*)d_in[12];
  p.k_b    = (const float*)d_in[13];
  p.k_m    = (const float*)d_in[14];
  p.k_v    = (const float*)d_in[15];
  p.v_w    = (const float*)d_in[16];
  p.v_g    = (const float*)d_in[17];
  p.v_b    = (const float*)d_in[18];
  p.v_m    = (const float*)d_in[19];
  p.v_v    = (const float*)d_in[20];
  p.proj_w = (const float*)d_in[21];
  p.proj_g = (const float*)d_in[22];
  p.proj_b = (const float*)d_in[23];
  p.proj_m = (const float*)d_in[24];
  p.proj_v = (const float*)d_in[25];
  p.attn_bias = (const float*)d_in[26];

  float* ws = (float*)d_ws;
  p.cbn    = ws;                                       // 4*B*64*N f32
  p.bias2  = p.cbn + (size_t)kNH * kB * kHD * kN;      // 4*N f32
  p.psc    = p.bias2 + kNH * kN;                       // 256 f32
  p.psh    = p.psc + kDIM;                             // 256 f32
  p.qkv_sc = p.psh + kDIM;                             // 4*96 f32
  p.qkv_sh = p.qkv_sc + kNH * 96;                      // 4*96 f32
  p.q_t  = (unsigned short*)(p.qkv_sh + kNH * 96);     // B*N*16 bf16
  p.k_t  = p.q_t + (size_t)kB * kN * kKD;              // B*N*16
  p.v_p  = p.k_t + (size_t)kB * kN * kKD;              // B*64*N
  p.o_bf = p.v_p + (size_t)kB * kD * kN;               // B*N*256
  p.w_bf = p.o_bf + (size_t)kB * kN * kDIM;            // 256*256
  p.x_t  = p.w_bf + (size_t)kDIM * kDIM;               // 4*B*N*64
  p.w_qk = p.x_t + (size_t)kNH * kB * kN * 64;         // 4*32*64
  p.w_vv = p.w_qk + (size_t)kNH * 32 * kHD;            // 4*64*64
  p.out = (float*)d_out;

  conv_prep_kernel<<<kB * kDIM, 256, 0, stream>>>(p);

  for (int head = 0; head < kNH; ++head) {
    qkv_mfma_kernel<<<600, 256, 0, stream>>>(p, head);
    attn_fused_kernel<<<kB * kQT, 256, 0, stream>>>(p, head);
  }

  proj_mfma_kernel<<<1600, 256, 0, stream>>>(p);
}